// Round 11
// baseline (78.600 us; speedup 1.0000x reference)
//
#include <hip/hip_runtime.h>
#include <math.h>

// Block DCT (8x8, stride 8) + soft histogram (121 sigmoid thresholds, gamma=1e6).
// gamma=1e6: sigmoid is a step function except within ~3e-5 of an integer
// threshold (exp(-1e6)==0.0f exactly in fp32) -> exact histogram with a rare
// sigmoid slow path. R2/R8 measured absmax == 0.0 vs the jax reference.
//
// R10/R11 = R2's proven construct vocabulary + the ownership transpose:
//   grid = 256 WGs x 64 threads (1 wave/WG). WG = (batch b, slice q), 64
//   blocks. Per-thread separable DCT; coefficients staged to LDS TRANSPOSED
//   (coef[k][block], stride 65). Lane t then owns ALL 64 values of
//   coefficient t and updates histogram row t only: LDS atomicAdds with ZERO
//   cross-lane same-address collisions (R2 had all 64 lanes hitting the same
//   k-row each step -> ~13 hot bins -> heavy same-address serialization).
//   Banks for hist row t: (25t + j) & 31 -> 2-way across 64 lanes = free.
//   Merge phase is shape-identical to R2 (LDS read + skip-zero global
//   atomicAdd, /1024 folded in). d_out pre-zeroed via hipMemsetAsync.
//   Deliberately absent (bisecting R4-R9's suspected toxic construct):
//   packed-u32 register histograms, local arrays, plain LDS float RMW,
//   numbered unroll pragmas, multiple __shared__ declarations.

#define HSTRIDE 121   // hist row stride (odd -> conflict-free)
#define CSTRIDE 65    // coef staging stride (odd -> conflict-free both ways)

__global__ __launch_bounds__(64) void dct_hist_kernel(
    const float* __restrict__ in,     // [16][256][256][1]
    const float* __restrict__ basis,  // [8][8][1][64]
    float* __restrict__ out)          // [16][120][64][1], pre-zeroed
{
    __shared__ float lds[64 * CSTRIDE + 64 * HSTRIDE];  // 16640 + 30976 B
    float* coef = lds;                   // [64][65]  coef[k][block]
    float* hist = lds + 64 * CSTRIDE;    // [64][121] row t owned by lane t

    const int t  = threadIdx.x;       // 0..63
    const int wg = blockIdx.x;        // 0..255
    const int b  = wg >> 4;           // batch 0..15
    const int q  = wg & 15;           // slice -> block-rows 2q, 2q+1

    // ---- zero histogram (coalesced, R2 shape) ----
    #pragma unroll
    for (int i = 0; i < HSTRIDE; ++i) hist[i * 64 + t] = 0.0f;
    __syncthreads();

    // ---- recover 1D DCT matrix C[a][x] (wave-uniform loads) ----
    // basis flat index (x*8+y)*64 + (8u+v); y=0, k=8a:
    // basis[x][0][8a] = C[a,x] * C[0,0], C[0,0] = 1/sqrt(8).
    float Cm[8][8];
    #pragma unroll
    for (int a = 0; a < 8; ++a)
        #pragma unroll
        for (int x = 0; x < 8; ++x)
            Cm[a][x] = basis[x * 512 + a * 8] * 2.8284271247461903f;

    // ---- per-thread 8x8 block DCT (fmaf order bit-identical to R2) ----
    const int by = q * 2 + (t >> 5);      // block-row 0..31
    const int bx = t & 31;                // block-col 0..31
    const float* p0 = in + ((b * 256 + by * 8) * 256 + bx * 8);

    float tv[8][8];  // tv[x][v] = sum_y C[v][y] * p[x][y]
    #pragma unroll
    for (int x = 0; x < 8; ++x) {
        const float4 r0 = *(const float4*)(p0 + x * 256);
        const float4 r1 = *(const float4*)(p0 + x * 256 + 4);
        const float p[8] = {r0.x, r0.y, r0.z, r0.w, r1.x, r1.y, r1.z, r1.w};
        #pragma unroll
        for (int v = 0; v < 8; ++v) {
            float s = 0.0f;
            #pragma unroll
            for (int y = 0; y < 8; ++y) s = fmaf(Cm[v][y], p[y], s);
            tv[x][v] = s;
        }
    }

    // ---- column pass; stage transposed: coef[k][t] ----
    #pragma unroll
    for (int u = 0; u < 8; ++u) {
        #pragma unroll
        for (int v = 0; v < 8; ++v) {
            float xv = 0.0f;
            #pragma unroll
            for (int x = 0; x < 8; ++x) xv = fmaf(Cm[u][x], tv[x][v], xv);
            coef[(u * 8 + v) * CSTRIDE + t] = xv;
        }
    }

    __syncthreads();

    // ---- phase 2: lane t owns coefficient t / histogram row t ----
    // 64 lanes -> 64 distinct rows: zero same-address collisions by design.
    const float* crow = &coef[t * CSTRIDE];
    float* hrow = &hist[t * HSTRIDE];
    const float EPS = 3e-5f;  // |gamma*d| > 30 -> sigmoid saturated in fp32

    for (int i = 0; i < 64; ++i) {
        const float xv = crow[i];
        const int j = (int)floorf(xv + 60.0f);  // threshold j-60 just below xv
        if (j >= -1 && j <= 120) {
            const float bf  = (float)j - 60.0f;
            const float dlo = xv - bf;
            const float dhi = xv - (bf + 1.0f);
            if (dlo > EPS && dhi < -EPS) {
                // fast path: both adjacent sigmoids fully saturated
                if (j >= 0 && j <= 119) atomicAdd(&hrow[j], 1.0f);
            } else {
                // slow path: exact sigmoid at the (at most one) live threshold
                const float slo = 1.0f / (1.0f + expf(-1e6f * dlo));
                const float shi = 1.0f / (1.0f + expf(-1e6f * dhi));
                if (j >= 0 && j <= 119) atomicAdd(&hrow[j],     slo - shi);
                if (j - 1 >= 0)         atomicAdd(&hrow[j - 1], 1.0f - slo);
                if (j + 1 <= 119)       atomicAdd(&hrow[j + 1], shi);
            }
        }
    }

    __syncthreads();

    // ---- merge (shape-identical to R2): lane t -> out[b][bin][t] ----
    float* outb = out + b * (120 * 64);
    for (int bin = 0; bin < 120; ++bin) {
        const float v = hist[t * HSTRIDE + bin];
        if (v != 0.0f) atomicAdd(&outb[bin * 64 + t], v * (1.0f / 1024.0f));
    }
}

extern "C" void kernel_launch(void* const* d_in, const int* in_sizes, int n_in,
                              void* d_out, int out_size, void* d_ws, size_t ws_size,
                              hipStream_t stream) {
    const float* inputs = (const float*)d_in[0];  // [16,256,256,1] fp32
    const float* basis  = (const float*)d_in[1];  // [8,8,1,64] fp32
    float* out = (float*)d_out;                   // [16,120,64,1] fp32

    // harness poisons d_out with 0xAA before every launch -> zero it first
    (void)hipMemsetAsync(out, 0, (size_t)out_size * sizeof(float), stream);

    dct_hist_kernel<<<dim3(256), dim3(64), 0, stream>>>(inputs, basis, out);
}

// Round 12
// 71.166 us; speedup vs baseline: 1.1045x; 1.1045x over previous
//
#include <hip/hip_runtime.h>
#include <math.h>

// Block DCT (8x8, stride 8) + soft histogram (121 sigmoid thresholds, gamma=1e6).
// gamma=1e6: sigmoid is a step function except within ~3e-5 of an integer
// threshold (exp(-1e6)==0.0f exactly in fp32) -> exact histogram with a rare
// sigmoid slow path. R2/R8/R11 measured absmax == 0.0 vs the jax reference.
//
// R12 = R11 (ownership transpose, zero same-address atomic collisions) with
// all serial LDS scalar reads replaced by pipelined ds_read_b128:
//   - coef rows stride 68 (272 B = 17x16 -> 16B-aligned float4 rows; banks
//     17t+i, 17 odd -> distinct mod 32). Phase 2: 16 float4 reads (was 64
//     scalar ds_reads, each ~120 cyc exposed at 1 wave/CU).
//   - hist rows stride 124 (496 B = 31x16; 31 coprime 32). Merge: 30 float4
//     reads (was 120 scalar).
// Everything else identical to R11: 256 WGs x 64 threads, per-thread separable
// DCT, lane t owns coefficient t / histogram row t, skip-zero global atomic
// merge with /1024 folded in, d_out pre-zeroed via hipMemsetAsync.

#define HSTRIDE 124   // hist row stride: 496 B, 16B-aligned, 31 coprime 32
#define CSTRIDE 68    // coef row stride: 272 B, 16B-aligned, 17 odd

__global__ __launch_bounds__(64) void dct_hist_kernel(
    const float* __restrict__ in,     // [16][256][256][1]
    const float* __restrict__ basis,  // [8][8][1][64]
    float* __restrict__ out)          // [16][120][64][1], pre-zeroed
{
    __shared__ float lds[64 * CSTRIDE + 64 * HSTRIDE];  // 17408 + 31744 B
    float* coef = lds;                   // [64][68]  coef[k][block]
    float* hist = lds + 64 * CSTRIDE;    // [64][124] row t owned by lane t

    const int t  = threadIdx.x;       // 0..63
    const int wg = blockIdx.x;        // 0..255
    const int b  = wg >> 4;           // batch 0..15
    const int q  = wg & 15;           // slice -> block-rows 2q, 2q+1

    // ---- zero histogram (coalesced) ----
    #pragma unroll
    for (int i = 0; i < HSTRIDE; ++i) hist[i * 64 + t] = 0.0f;
    __syncthreads();

    // ---- recover 1D DCT matrix C[a][x] (wave-uniform loads) ----
    // basis flat index (x*8+y)*64 + (8u+v); y=0, k=8a:
    // basis[x][0][8a] = C[a,x] * C[0,0], C[0,0] = 1/sqrt(8).
    float Cm[8][8];
    #pragma unroll
    for (int a = 0; a < 8; ++a)
        #pragma unroll
        for (int x = 0; x < 8; ++x)
            Cm[a][x] = basis[x * 512 + a * 8] * 2.8284271247461903f;

    // ---- per-thread 8x8 block DCT (fmaf order bit-identical to R2) ----
    const int by = q * 2 + (t >> 5);      // block-row 0..31
    const int bx = t & 31;                // block-col 0..31
    const float* p0 = in + ((b * 256 + by * 8) * 256 + bx * 8);

    float tv[8][8];  // tv[x][v] = sum_y C[v][y] * p[x][y]
    #pragma unroll
    for (int x = 0; x < 8; ++x) {
        const float4 r0 = *(const float4*)(p0 + x * 256);
        const float4 r1 = *(const float4*)(p0 + x * 256 + 4);
        const float p[8] = {r0.x, r0.y, r0.z, r0.w, r1.x, r1.y, r1.z, r1.w};
        #pragma unroll
        for (int v = 0; v < 8; ++v) {
            float s = 0.0f;
            #pragma unroll
            for (int y = 0; y < 8; ++y) s = fmaf(Cm[v][y], p[y], s);
            tv[x][v] = s;
        }
    }

    // ---- column pass; stage transposed: coef[k][t] (lane-consecutive writes)
    #pragma unroll
    for (int u = 0; u < 8; ++u) {
        #pragma unroll
        for (int v = 0; v < 8; ++v) {
            float xv = 0.0f;
            #pragma unroll
            for (int x = 0; x < 8; ++x) xv = fmaf(Cm[u][x], tv[x][v], xv);
            coef[(u * 8 + v) * CSTRIDE + t] = xv;
        }
    }

    __syncthreads();

    // ---- phase 2: lane t owns coefficient t / histogram row t ----
    // 16 pipelined ds_read_b128 replace 64 latency-exposed scalar reads.
    const float* crow = &coef[t * CSTRIDE];
    float* hrow = &hist[t * HSTRIDE];
    const float EPS = 3e-5f;  // |gamma*d| > 30 -> sigmoid saturated in fp32

    #pragma unroll
    for (int c = 0; c < 16; ++c) {
        const float4 v4 = *(const float4*)(crow + 4 * c);
        const float vals[4] = {v4.x, v4.y, v4.z, v4.w};
        #pragma unroll
        for (int s = 0; s < 4; ++s) {
            const float xv = vals[s];
            const int j = (int)floorf(xv + 60.0f);  // threshold j-60 just below xv
            if (j >= -1 && j <= 120) {
                const float bf  = (float)j - 60.0f;
                const float dlo = xv - bf;
                const float dhi = xv - (bf + 1.0f);
                if (dlo > EPS && dhi < -EPS) {
                    // fast path: both adjacent sigmoids fully saturated
                    if (j >= 0 && j <= 119) atomicAdd(&hrow[j], 1.0f);
                } else {
                    // slow path: exact sigmoid at the (at most one) live threshold
                    const float slo = 1.0f / (1.0f + expf(-1e6f * dlo));
                    const float shi = 1.0f / (1.0f + expf(-1e6f * dhi));
                    if (j >= 0 && j <= 119) atomicAdd(&hrow[j],     slo - shi);
                    if (j - 1 >= 0)         atomicAdd(&hrow[j - 1], 1.0f - slo);
                    if (j + 1 <= 119)       atomicAdd(&hrow[j + 1], shi);
                }
            }
        }
    }

    // no barrier needed: each lane reads only its own hrow below

    // ---- merge: lane t -> out[b][bin][t]; 30 float4 reads, skip-zero atomics
    float* outb = out + b * (120 * 64);
    #pragma unroll
    for (int c = 0; c < 30; ++c) {
        const float4 h4 = *(const float4*)(hrow + 4 * c);
        const float hv[4] = {h4.x, h4.y, h4.z, h4.w};
        #pragma unroll
        for (int s = 0; s < 4; ++s) {
            const float v = hv[s];
            if (v != 0.0f)
                atomicAdd(&outb[(4 * c + s) * 64 + t], v * (1.0f / 1024.0f));
        }
    }
}

extern "C" void kernel_launch(void* const* d_in, const int* in_sizes, int n_in,
                              void* d_out, int out_size, void* d_ws, size_t ws_size,
                              hipStream_t stream) {
    const float* inputs = (const float*)d_in[0];  // [16,256,256,1] fp32
    const float* basis  = (const float*)d_in[1];  // [8,8,1,64] fp32
    float* out = (float*)d_out;                   // [16,120,64,1] fp32

    // harness poisons d_out with 0xAA before every launch -> zero it first
    (void)hipMemsetAsync(out, 0, (size_t)out_size * sizeof(float), stream);

    dct_hist_kernel<<<dim3(256), dim3(64), 0, stream>>>(inputs, basis, out);
}

// Round 13
// 64.766 us; speedup vs baseline: 1.2136x; 1.0988x over previous
//
#include <hip/hip_runtime.h>
#include <math.h>

// Block DCT (8x8, stride 8) + soft histogram (121 sigmoid thresholds, gamma=1e6).
// gamma=1e6: sigmoid is a step function except within ~3e-5 of an integer
// threshold (exp(-1e6)==0.0f exactly in fp32) -> exact histogram with a rare
// sigmoid slow path. R2/R8/R11/R12 measured absmax == 0.0 vs the reference.
//
// R13: attack the REAL bottleneck seen in R12's profile (50 us, VALUBusy 1.5%,
// occupancy 2.5% = 1 wave/CU, everything idle -> pure exposed latency):
//   4 threads per 8x8 block -> 1024 WGs x 64 threads = 4 waves/CU (4x TLP)
//   and 4x shorter per-wave serial chains.
//   Thread (i = t>>2, h = t&3): row-pass rows {2h,2h+1} of block i (4
//   coalesced float4 loads), stage tv to LDS [16][73] (i-stride 73 -> 9i mod
//   32 distinct banks); col-pass u in {2h,2h+1} using C rows 2h,2h+1 held in
//   registers (loaded per-lane, compile-time indexing only); stage
//   coef[k][i] ([64][17], conflict-free both ways).
//   Lane k owns coefficient k over the WG's 16 blocks: histogram lives in 6
//   packed-u32 REGISTERS (24 bins [48,72), 4x8-bit cells, max 16 < 255).
//   N(0,1) coefficients never leave |x|<12, so out-of-window fast hits and
//   fractional slow-path hits (both ultra-rare) go straight to global
//   atomics. Merge: skip-zero global atomicAdd of the 24 window counts,
//   /1024 folded in. d_out pre-zeroed via hipMemsetAsync.
//   LDS: 4672+4352 = 9 KB (was 49 KB). No LDS hist, no LDS atomics at all.

__global__ __launch_bounds__(64) void dct_hist_kernel(
    const float* __restrict__ in,     // [16][256][256][1]
    const float* __restrict__ basis,  // [8][8][1][64]
    float* __restrict__ out)          // [16][120][64][1], pre-zeroed
{
    __shared__ float tvs[16 * 73];    // 4672 B: tv[i][x][v] at i*73 + x*9 + v
    __shared__ float coef[64 * 17];   // 4352 B: coef[k][i]  at k*17 + i

    const int t  = threadIdx.x;       // 0..63
    const int wg = blockIdx.x;        // 0..1023
    const int b  = wg >> 6;           // batch 0..15
    const int g  = wg & 63;           // group: 16 blocks of batch b
    const int by = g >> 1;            // block-row 0..31
    const int bx0 = (g & 1) * 16;     // block-col half

    const int i = t >> 2;             // block-in-group 0..15
    const int h = t & 3;              // quarter 0..3

    const float SQRT8 = 2.8284271247461903f;

    // ---- full 1D DCT matrix C[v][y] (wave-uniform loads; row pass needs all v)
    // basis[x][0][8a] = C[a,x] * C[0,0], C[0,0] = 1/sqrt(8).
    float Cm[8][8];
    #pragma unroll
    for (int a = 0; a < 8; ++a)
        #pragma unroll
        for (int x = 0; x < 8; ++x)
            Cm[a][x] = basis[x * 512 + a * 8] * SQRT8;

    // ---- row pass: rows 2h, 2h+1 of block i (fmaf order bit-identical) ----
    const float* p0 = in + ((b * 256 + by * 8) * 256 + (bx0 + i) * 8);
    #pragma unroll
    for (int xl = 0; xl < 2; ++xl) {
        const int x = 2 * h + xl;
        const float4 r0 = *(const float4*)(p0 + x * 256);
        const float4 r1 = *(const float4*)(p0 + x * 256 + 4);
        const float p[8] = {r0.x, r0.y, r0.z, r0.w, r1.x, r1.y, r1.z, r1.w};
        #pragma unroll
        for (int v = 0; v < 8; ++v) {
            float s = 0.0f;
            #pragma unroll
            for (int y = 0; y < 8; ++y) s = fmaf(Cm[v][y], p[y], s);
            tvs[i * 73 + x * 9 + v] = s;
        }
    }

    // ---- C rows 2h, 2h+1 for the column pass (per-lane, static indexing) ----
    float Cu0[8], Cu1[8];
    #pragma unroll
    for (int x = 0; x < 8; ++x) {
        Cu0[x] = basis[x * 512 + (2 * h) * 8] * SQRT8;
        Cu1[x] = basis[x * 512 + (2 * h + 1) * 8] * SQRT8;
    }

    __syncthreads();

    // ---- column pass: u in {2h, 2h+1}, all v; stage coef[k][i] ----
    #pragma unroll
    for (int v = 0; v < 8; ++v) {
        float tcol[8];
        #pragma unroll
        for (int x = 0; x < 8; ++x) tcol[x] = tvs[i * 73 + x * 9 + v];
        float xv0 = 0.0f, xv1 = 0.0f;
        #pragma unroll
        for (int x = 0; x < 8; ++x) {
            xv0 = fmaf(Cu0[x], tcol[x], xv0);
            xv1 = fmaf(Cu1[x], tcol[x], xv1);
        }
        coef[((2 * h) * 8 + v) * 17 + i] = xv0;
        coef[((2 * h + 1) * 8 + v) * 17 + i] = xv1;
    }

    __syncthreads();

    // ---- phase 2: lane k (=t) owns coefficient k over 16 blocks ----
    unsigned h0 = 0, h1 = 0, h2 = 0, h3 = 0, h4 = 0, h5 = 0;
    float* outb = out + b * (120 * 64);
    const float EPS = 3e-5f;  // |gamma*d| > 30 -> sigmoid saturated in fp32

    #pragma unroll
    for (int blk = 0; blk < 16; ++blk) {
        const float xv = coef[t * 17 + blk];
        const int j = (int)floorf(xv + 60.0f);  // threshold j-60 just below xv
        if (j >= -1 && j <= 120) {
            const float bf  = (float)j - 60.0f;
            const float dlo = xv - bf;
            const float dhi = xv - (bf + 1.0f);
            if (dlo > EPS && dhi < -EPS) {
                // fast path: both adjacent sigmoids fully saturated -> +1 to bin j
                const unsigned w = (unsigned)(j - 48);
                if (w < 24u) {
                    const unsigned inc = 1u << (8 * (w & 3));
                    const unsigned sel = w >> 2;
                    h0 += (sel == 0) ? inc : 0u;
                    h1 += (sel == 1) ? inc : 0u;
                    h2 += (sel == 2) ? inc : 0u;
                    h3 += (sel == 3) ? inc : 0u;
                    h4 += (sel == 4) ? inc : 0u;
                    h5 += (sel == 5) ? inc : 0u;
                } else if (j >= 0 && j <= 119) {
                    // |x| >= 12 sigma: never in practice, correct if it happens
                    atomicAdd(&outb[j * 64 + t], 1.0f / 1024.0f);
                }
            } else {
                // slow path: exact sigmoid at the (at most one) live threshold
                const float slo = 1.0f / (1.0f + expf(-1e6f * dlo));
                const float shi = 1.0f / (1.0f + expf(-1e6f * dhi));
                if (j >= 0 && j <= 119)
                    atomicAdd(&outb[j * 64 + t], (slo - shi) * (1.0f / 1024.0f));
                if (j - 1 >= 0)
                    atomicAdd(&outb[(j - 1) * 64 + t], (1.0f - slo) * (1.0f / 1024.0f));
                if (j + 1 <= 119)
                    atomicAdd(&outb[(j + 1) * 64 + t], shi * (1.0f / 1024.0f));
            }
        }
    }

    // ---- merge: skip-zero global atomics of the 24 window counts ----
    const unsigned hw[6] = {h0, h1, h2, h3, h4, h5};
    #pragma unroll
    for (int w = 0; w < 24; ++w) {
        const float cnt = (float)((hw[w >> 2] >> (8 * (w & 3))) & 255u);
        if (cnt != 0.0f)
            atomicAdd(&outb[(48 + w) * 64 + t], cnt * (1.0f / 1024.0f));
    }
}

extern "C" void kernel_launch(void* const* d_in, const int* in_sizes, int n_in,
                              void* d_out, int out_size, void* d_ws, size_t ws_size,
                              hipStream_t stream) {
    const float* inputs = (const float*)d_in[0];  // [16,256,256,1] fp32
    const float* basis  = (const float*)d_in[1];  // [8,8,1,64] fp32
    float* out = (float*)d_out;                   // [16,120,64,1] fp32

    // harness poisons d_out with 0xAA before every launch -> zero it first
    (void)hipMemsetAsync(out, 0, (size_t)out_size * sizeof(float), stream);

    dct_hist_kernel<<<dim3(1024), dim3(64), 0, stream>>>(inputs, basis, out);
}